// Round 9
// baseline (177.004 us; speedup 1.0000x reference)
//
#include <hip/hip_runtime.h>
#include <cstdint>
#include <cstddef>

// Problem constants
// B=16, N=300, D=256, HEADS=8, HD=32, L=8500, TP=16, HID=512
// SPATIAL = (80,80),(40,40),(20,20),(10,10); starts 0,6400,8000,8400

typedef __attribute__((ext_vector_type(8))) short bf16x8;
typedef __attribute__((ext_vector_type(4))) float f32x4;

__device__ __forceinline__ unsigned short f2bf(float f) {
  unsigned int u = __float_as_uint(f);
  u = (u + 0x7fffu + ((u >> 16) & 1u)) >> 16;   // round-to-nearest-even
  return (unsigned short)u;
}
__device__ __forceinline__ unsigned int pack2bf(float lo, float hi) {
  return ((unsigned int)f2bf(hi) << 16) | (unsigned int)f2bf(lo);
}

// ---------------------------------------------------------------------------
// conv_w: one-pass f32 -> bf16 conversion of target + all GEMM weights.
// grid (1200, 8); tensor selected by blockIdx.y; 4 elems/thread.
// ---------------------------------------------------------------------------
__global__ __launch_bounds__(256) void conv_w(
    const float* __restrict__ s0, const float* __restrict__ s1,
    const float* __restrict__ s2, const float* __restrict__ s3,
    const float* __restrict__ s4, const float* __restrict__ s5,
    const float* __restrict__ s6, const float* __restrict__ s7,
    unsigned short* __restrict__ d0, unsigned short* __restrict__ d1,
    unsigned short* __restrict__ d2, unsigned short* __restrict__ d3,
    unsigned short* __restrict__ d4, unsigned short* __restrict__ d5,
    unsigned short* __restrict__ d6, unsigned short* __restrict__ d7)
{
  const int sizes[8] = {1228800, 196608, 65536, 65536, 32768, 65536, 262144, 131072};
  const float* s; unsigned short* d;
  switch (blockIdx.y) {
    case 0: s = s0; d = d0; break;
    case 1: s = s1; d = d1; break;
    case 2: s = s2; d = d2; break;
    case 3: s = s3; d = d3; break;
    case 4: s = s4; d = d4; break;
    case 5: s = s5; d = d5; break;
    case 6: s = s6; d = d6; break;
    default: s = s7; d = d7; break;
  }
  const int n = sizes[blockIdx.y];
  const int i4 = (blockIdx.x * 256 + threadIdx.x) * 4;
  if (i4 >= n) return;
  float4 v = *(const float4*)&s[i4];
  uint2 p;
  p.x = pack2bf(v.x, v.y);
  p.y = pack2bf(v.z, v.w);
  *(uint2*)&d[i4] = p;
}

// ---------------------------------------------------------------------------
// bf16-in GEMM core: acc(64x128 tile) = A16(M,K)@W16(N,K)^T. Staging is pure
// 16B chunk copies (no VALU pack): per K64-step per thread 2 A-chunks +
// 4 W-chunks. Register-prefetch double-step pipeline; stride-72 LDS rows.
// ---------------------------------------------------------------------------
__device__ __forceinline__ void gemm_core16(
    const unsigned short* __restrict__ A16, const unsigned short* __restrict__ W16,
    int K, int row0, int col0,
    unsigned short* As, unsigned short* Ws, f32x4 acc[4][2])
{
  const int t = threadIdx.x, wave = t >> 6, lane = t & 63;
  const int lr = lane & 15, g = lane >> 4;

  uint4 rA[2], rW[4];
#pragma unroll
  for (int i = 0; i < 2; ++i) {
    const int c = t + i * 256, row = c >> 3, sl = c & 7;
    rA[i] = *(const uint4*)&A16[(size_t)(row0 + row) * K + sl * 8];
  }
#pragma unroll
  for (int j = 0; j < 4; ++j) {
    const int c = t + j * 256, row = c >> 3, sl = c & 7;
    rW[j] = *(const uint4*)&W16[(size_t)(col0 + row) * K + sl * 8];
  }

  for (int k0 = 0; k0 < K; k0 += 64) {
    __syncthreads();   // prev MFMA reads done
#pragma unroll
    for (int i = 0; i < 2; ++i) {
      const int c = t + i * 256, row = c >> 3, sl = c & 7;
      *(uint4*)&As[row * 72 + sl * 8] = rA[i];
    }
#pragma unroll
    for (int j = 0; j < 4; ++j) {
      const int c = t + j * 256, row = c >> 3, sl = c & 7;
      *(uint4*)&Ws[row * 72 + sl * 8] = rW[j];
    }
    __syncthreads();   // staged data visible

    if (k0 + 64 < K) {
#pragma unroll
      for (int i = 0; i < 2; ++i) {
        const int c = t + i * 256, row = c >> 3, sl = c & 7;
        rA[i] = *(const uint4*)&A16[(size_t)(row0 + row) * K + k0 + 64 + sl * 8];
      }
#pragma unroll
      for (int j = 0; j < 4; ++j) {
        const int c = t + j * 256, row = c >> 3, sl = c & 7;
        rW[j] = *(const uint4*)&W16[(size_t)(col0 + row) * K + k0 + 64 + sl * 8];
      }
    }

#pragma unroll
    for (int ks = 0; ks < 2; ++ks) {
      bf16x8 aA[4], bB[2];
#pragma unroll
      for (int i = 0; i < 4; ++i)
        aA[i] = *(const bf16x8*)&As[(i * 16 + lr) * 72 + ks * 32 + g * 8];
#pragma unroll
      for (int j = 0; j < 2; ++j)
        bB[j] = *(const bf16x8*)&Ws[(wave * 32 + j * 16 + lr) * 72 + ks * 32 + g * 8];
#pragma unroll
      for (int i = 0; i < 4; ++i)
#pragma unroll
        for (int j = 0; j < 2; ++j)
          acc[i][j] = __builtin_amdgcn_mfma_f32_16x16x32_bf16(aA[i], bB[j], acc[i][j], 0, 0, 0);
    }
  }
}

// Generic: C f32 = A16@W16^T + bias
__global__ __launch_bounds__(256) void gemm_mfma16(
    const unsigned short* __restrict__ A16, const unsigned short* __restrict__ W16,
    const float* __restrict__ bias, float* __restrict__ C, int N, int K)
{
  __shared__ __align__(16) unsigned short As[64 * 72];
  __shared__ __align__(16) unsigned short Ws[128 * 72];
  const int row0 = blockIdx.y * 64, col0 = blockIdx.x * 128;
  f32x4 acc[4][2] = {};
  gemm_core16(A16, W16, K, row0, col0, As, Ws, acc);

  const int t = threadIdx.x, wave = t >> 6, lane = t & 63;
  const int lr = lane & 15, g = lane >> 4;
  const float b0 = bias[col0 + wave * 32 + lr];
  const float b1 = bias[col0 + wave * 32 + 16 + lr];
#pragma unroll
  for (int i = 0; i < 4; ++i) {
#pragma unroll
    for (int r = 0; r < 4; ++r) {
      const int row = row0 + i * 16 + g * 4 + r;
      float* dst = &C[(size_t)row * N + col0 + wave * 32 + lr];
      dst[0]  = acc[i][0][r] + b0;
      dst[16] = acc[i][1][r] + b1;
    }
  }
}

// OF (N=256, blocks 0,1) and AW (N=128, block 2) share input X16.
__global__ __launch_bounds__(256) void gemm_offaw16(
    const unsigned short* __restrict__ X16,
    const unsigned short* __restrict__ off16, const float* __restrict__ off_b,
    float* __restrict__ OF,
    const unsigned short* __restrict__ aw16, const float* __restrict__ aw_b,
    float* __restrict__ AW)
{
  __shared__ __align__(16) unsigned short As[64 * 72];
  __shared__ __align__(16) unsigned short Ws[128 * 72];
  const int row0 = blockIdx.y * 64;
  const bool isOff = blockIdx.x < 2;
  const int col0 = isOff ? blockIdx.x * 128 : 0;
  const unsigned short* W16 = isOff ? off16 : aw16;
  const float* bias = isOff ? off_b : aw_b;
  float* C = isOff ? OF : AW;
  const int N = isOff ? 256 : 128;

  f32x4 acc[4][2] = {};
  gemm_core16(X16, W16, 256, row0, col0, As, Ws, acc);

  const int t = threadIdx.x, wave = t >> 6, lane = t & 63;
  const int lr = lane & 15, g = lane >> 4;
  const float b0 = bias[col0 + wave * 32 + lr];
  const float b1 = bias[col0 + wave * 32 + 16 + lr];
#pragma unroll
  for (int i = 0; i < 4; ++i) {
#pragma unroll
    for (int r = 0; r < 4; ++r) {
      const int row = row0 + i * 16 + g * 4 + r;
      float* dst = &C[(size_t)row * N + col0 + wave * 32 + lr];
      dst[0]  = acc[i][0][r] + b0;
      dst[16] = acc[i][1][r] + b1;
    }
  }
}

// ---------------------------------------------------------------------------
// QKV GEMM (A16=target16) with fused bf16 repack epilogue.
//   Qb/Kb: [bh][304][32]; VTb: [bh][32][320] (cols 300..319 zeroed by y==74)
// ---------------------------------------------------------------------------
__global__ __launch_bounds__(256) void gemm_qkv16(
    const unsigned short* __restrict__ T16, const unsigned short* __restrict__ W16,
    const float* __restrict__ bias,
    unsigned short* __restrict__ Qb, unsigned short* __restrict__ Kb,
    unsigned short* __restrict__ VTb)
{
  __shared__ __align__(16) unsigned short As[64 * 72];
  __shared__ __align__(16) unsigned short Ws[128 * 72];
  const int row0 = blockIdx.y * 64, col0 = blockIdx.x * 128;
  f32x4 acc[4][2] = {};
  gemm_core16(T16, W16, 256, row0, col0, As, Ws, acc);

  const int t = threadIdx.x, wave = t >> 6, lane = t & 63;
  const int lr = lane & 15, g = lane >> 4;
  const int bx = blockIdx.x;
  const float scale = 0.17677669529663687f;  // 1/sqrt(32)
  const float b0 = bias[col0 + wave * 32 + lr];
  const float b1 = bias[col0 + wave * 32 + 16 + lr];

  if (bx < 4) {
    unsigned short* dstT = (bx < 2) ? Qb : Kb;
    const float mul = (bx < 2) ? scale : 1.0f;
#pragma unroll
    for (int i = 0; i < 4; ++i) {
#pragma unroll
      for (int r = 0; r < 4; ++r) {
        const int row = row0 + i * 16 + g * 4 + r;
        const int b = row / 300, n = row - b * 300;
#pragma unroll
        for (int j = 0; j < 2; ++j) {
          const int c768 = col0 + wave * 32 + j * 16 + lr;
          const int h = (c768 >> 5) & 7, c = c768 & 31;
          const float v = (acc[i][j][r] + (j ? b1 : b0)) * mul;
          dstT[((size_t)(b * 8 + h) * 304 + n) * 32 + c] = f2bf(v);
        }
      }
    }
  } else {
    __syncthreads();  // everyone done reading Ws from the K-loop
#pragma unroll
    for (int i = 0; i < 4; ++i)
#pragma unroll
      for (int r = 0; r < 4; ++r)
#pragma unroll
        for (int j = 0; j < 2; ++j) {
          const int c_local = wave * 32 + j * 16 + lr;
          const int n_local = i * 16 + g * 4 + r;
          Ws[c_local * 72 + n_local] = f2bf(acc[i][j][r] + (j ? b1 : b0));
        }
    __syncthreads();
    for (int idx = t; idx < 128 * 64; idx += 256) {
      const int c_local = idx >> 6, n_local = idx & 63;
      const int row = row0 + n_local;
      const int b = row / 300, n = row - b * 300;
      const int c768 = col0 + c_local;
      const int h = (c768 >> 5) & 7, c = c768 & 31;
      VTb[((size_t)(b * 8 + h) * 32 + c) * 320 + n] = Ws[c_local * 72 + n_local];
    }
    if (blockIdx.y == 74) {
      for (int idx = t; idx < 64 * 32 * 20; idx += 256) {
        const int n = 300 + idx % 20;
        const int rem = idx / 20;
        const int c = rem & 31, bh4 = rem >> 5;
        const int b = bh4 >> 2, h = (bx - 4) * 4 + (bh4 & 3);
        VTb[((size_t)(b * 8 + h) * 32 + c) * 320 + n] = 0;
      }
    }
  }
}

// ---------------------------------------------------------------------------
// Fused GEMM + residual + [clip] + RMSNorm. Tile 32x256 (full row), 150
// blocks, prefetch pipeline. A is bf16 (1 chunk/thread) except SWIGLU
// (f32 Hb, silu in staging). Writes C f32 and optional bf16 mirror.
// ---------------------------------------------------------------------------
template <bool SWIGLU>
__global__ __launch_bounds__(256) void gemm_rms32_16(
    const void* __restrict__ Ain, const unsigned short* __restrict__ W16,
    const float* __restrict__ bias, const float* __restrict__ res,
    const float* __restrict__ nw, float* __restrict__ C,
    unsigned short* __restrict__ Cmir, int K, int clip)
{
  __shared__ __align__(16) unsigned short As[32 * 72];
  __shared__ __align__(16) unsigned short Ws[256 * 72];
  __shared__ float rsum[32][4];

  const int t = threadIdx.x, wave = t >> 6, lane = t & 63;
  const int lr = lane & 15, g = lane >> 4;
  const int row0 = blockIdx.x * 32;
  const int sr = t >> 4, sc = (t & 15) * 4;

  uint4 rA;
  float4 ra1[2], ra2[2];
  uint4 rW[8];
  const unsigned short* A16 = (const unsigned short*)Ain;
  const float* Af = (const float*)Ain;

  if (SWIGLU) {
#pragma unroll
    for (int i = 0; i < 2; ++i) {
      ra1[i] = *(const float4*)&Af[(size_t)(row0 + sr + 16 * i) * 1024 + sc];
      ra2[i] = *(const float4*)&Af[(size_t)(row0 + sr + 16 * i) * 1024 + 512 + sc];
    }
  } else {
    const int row = t >> 3, sl = t & 7;
    rA = *(const uint4*)&A16[(size_t)(row0 + row) * K + sl * 8];
  }
#pragma unroll
  for (int j = 0; j < 8; ++j) {
    const int c = t + j * 256, row = c >> 3, sl = c & 7;
    rW[j] = *(const uint4*)&W16[(size_t)row * K + sl * 8];
  }

  f32x4 acc[2][4] = {};

  for (int k0 = 0; k0 < K; k0 += 64) {
    __syncthreads();
    if (SWIGLU) {
#pragma unroll
      for (int i = 0; i < 2; ++i) {
        float4 v;
        v.x = ra1[i].x / (1.f + __expf(-ra1[i].x)) * ra2[i].x;
        v.y = ra1[i].y / (1.f + __expf(-ra1[i].y)) * ra2[i].y;
        v.z = ra1[i].z / (1.f + __expf(-ra1[i].z)) * ra2[i].z;
        v.w = ra1[i].w / (1.f + __expf(-ra1[i].w)) * ra2[i].w;
        uint2 p;
        p.x = pack2bf(v.x, v.y);
        p.y = pack2bf(v.z, v.w);
        *(uint2*)&As[(sr + 16 * i) * 72 + sc] = p;
      }
    } else {
      const int row = t >> 3, sl = t & 7;
      *(uint4*)&As[row * 72 + sl * 8] = rA;
    }
#pragma unroll
    for (int j = 0; j < 8; ++j) {
      const int c = t + j * 256, row = c >> 3, sl = c & 7;
      *(uint4*)&Ws[row * 72 + sl * 8] = rW[j];
    }
    __syncthreads();

    if (k0 + 64 < K) {
      if (SWIGLU) {
#pragma unroll
        for (int i = 0; i < 2; ++i) {
          ra1[i] = *(const float4*)&Af[(size_t)(row0 + sr + 16 * i) * 1024 + k0 + 64 + sc];
          ra2[i] = *(const float4*)&Af[(size_t)(row0 + sr + 16 * i) * 1024 + 512 + k0 + 64 + sc];
        }
      } else {
        const int row = t >> 3, sl = t & 7;
        rA = *(const uint4*)&A16[(size_t)(row0 + row) * K + k0 + 64 + sl * 8];
      }
#pragma unroll
      for (int j = 0; j < 8; ++j) {
        const int c = t + j * 256, row = c >> 3, sl = c & 7;
        rW[j] = *(const uint4*)&W16[(size_t)row * K + k0 + 64 + sl * 8];
      }
    }

#pragma unroll
    for (int ks = 0; ks < 2; ++ks) {
      bf16x8 aA[2], bB[4];
#pragma unroll
      for (int i = 0; i < 2; ++i)
        aA[i] = *(const bf16x8*)&As[(i * 16 + lr) * 72 + ks * 32 + g * 8];
#pragma unroll
      for (int j = 0; j < 4; ++j)
        bB[j] = *(const bf16x8*)&Ws[(wave * 64 + j * 16 + lr) * 72 + ks * 32 + g * 8];
#pragma unroll
      for (int i = 0; i < 2; ++i)
#pragma unroll
        for (int j = 0; j < 4; ++j)
          acc[i][j] = __builtin_amdgcn_mfma_f32_16x16x32_bf16(aA[i], bB[j], acc[i][j], 0, 0, 0);
    }
  }

  // ---- epilogue: v = acc + bias + res [clip]; row sumsq; rmsnorm; store
  float bj[4], wj[4];
#pragma unroll
  for (int j = 0; j < 4; ++j) {
    bj[j] = bias[wave * 64 + j * 16 + lr];
    wj[j] = nw[wave * 64 + j * 16 + lr];
  }

  float part[2][4] = {};
#pragma unroll
  for (int i = 0; i < 2; ++i) {
#pragma unroll
    for (int r = 0; r < 4; ++r) {
      const int row = row0 + i * 16 + g * 4 + r;
#pragma unroll
      for (int j = 0; j < 4; ++j) {
        const int col = wave * 64 + j * 16 + lr;
        float v = acc[i][j][r] + bj[j] + res[(size_t)row * 256 + col];
        if (clip) v = fminf(fmaxf(v, -65504.f), 65504.f);
        acc[i][j][r] = v;
        part[i][r] += v * v;
      }
    }
  }
#pragma unroll
  for (int i = 0; i < 2; ++i)
#pragma unroll
    for (int r = 0; r < 4; ++r) {
      float s = part[i][r];
      s += __shfl_xor(s, 1);
      s += __shfl_xor(s, 2);
      s += __shfl_xor(s, 4);
      s += __shfl_xor(s, 8);
      part[i][r] = s;
    }
  if (lr == 0) {
#pragma unroll
    for (int i = 0; i < 2; ++i)
#pragma unroll
      for (int r = 0; r < 4; ++r)
        rsum[i * 16 + g * 4 + r][wave] = part[i][r];
  }
  __syncthreads();

#pragma unroll
  for (int i = 0; i < 2; ++i) {
#pragma unroll
    for (int r = 0; r < 4; ++r) {
      const int row = row0 + i * 16 + g * 4 + r;
      const f32x4 q = *(const f32x4*)&rsum[i * 16 + g * 4 + r][0];
      const float tot = q[0] + q[1] + q[2] + q[3];
      const float scale = rsqrtf(tot * (1.0f / 256.0f) + 1e-6f);
#pragma unroll
      for (int j = 0; j < 4; ++j) {
        const int col = wave * 64 + j * 16 + lr;
        const float o = acc[i][j][r] * scale * wj[j];
        C[(size_t)row * 256 + col] = o;
        if (Cmir) Cmir[(size_t)row * 256 + col] = f2bf(o);
      }
    }
  }
}

// ---------------------------------------------------------------------------
// Staging-free MFMA self-attention core -> SA16 (bf16). grid (19, B*H),
// block = 1 wave; fragments are direct 16B global loads (L2-hot).
// ---------------------------------------------------------------------------
__global__ __launch_bounds__(64) void attn_core(
    const unsigned short* __restrict__ Qb, const unsigned short* __restrict__ Kb,
    const unsigned short* __restrict__ VTb, unsigned short* __restrict__ sa16)
{
  __shared__ __align__(16) unsigned short P[16 * 40];
  const int gt = blockIdx.x;               // q-tile 0..18
  const int bh = blockIdx.y, b = bh >> 3, h = bh & 7;
  const int lane = threadIdx.x, lr = lane & 15, g = lane >> 4;

  const unsigned short* Kbase = Kb + (size_t)bh * 304 * 32;
  const unsigned short* Vbase = VTb + (size_t)bh * 32 * 320;

  bf16x8 aQ = *(const bf16x8*)&Qb[((size_t)bh * 304 + gt * 16 + lr) * 32 + g * 8];

  f32x4 s[19];
  const f32x4 zero = {0.f, 0.f, 0.f, 0.f};
#pragma unroll
  for (int kt = 0; kt < 19; ++kt) {
    bf16x8 bK = *(const bf16x8*)&Kbase[(kt * 16 + lr) * 32 + g * 8];
    s[kt] = __builtin_amdgcn_mfma_f32_16x16x32_bf16(aQ, bK, zero, 0, 0, 0);
  }
  if (lr >= 12) {  // mask cols 300..303
    s[18][0] = -1e30f; s[18][1] = -1e30f; s[18][2] = -1e30f; s[18][3] = -1e30f;
  }

  float inv[4];
#pragma unroll
  for (int r = 0; r < 4; ++r) {
    float m = -1e30f;
#pragma unroll
    for (int kt = 0; kt < 19; ++kt) m = fmaxf(m, s[kt][r]);
#pragma unroll
    for (int o = 8; o >= 1; o >>= 1) m = fmaxf(m, __shfl_xor(m, o));
    float sum = 0.f;
#pragma unroll
    for (int kt = 0; kt < 19; ++kt) {
      float e = __expf(s[kt][r] - m);
      s[kt][r] = e;
      sum += e;
    }
#pragma unroll
    for (int o = 8; o >= 1; o >>= 1) sum += __shfl_xor(sum, o);
    inv[r] = 1.f / sum;
  }

  f32x4 o0 = {0.f, 0.f, 0.f, 0.f}, o1 = {0.f, 0.f, 0.f, 0.f};
#pragma unroll
  for (int ks = 0; ks < 10; ++ks) {
#pragma unroll
    for (int tp = 0; tp < 2; ++tp) {
      const int kt = ks * 2 + tp;
#pragma unroll
      for (int r = 0; r < 4; ++r) {
        unsigned short pv = (kt < 19) ? f2bf(s[kt][r]) : (unsigned short)0;
        P[(g * 4 + r) * 40 + tp * 16 + lr] = pv;
      }
    }
    asm volatile("s_waitcnt lgkmcnt(0)" ::: "memory");
    __builtin_amdgcn_sched_barrier(0);
    bf16x8 aP = *(const bf16x8*)&P[lr * 40 + g * 8];
    bf16x8 bV0 = *(const bf16x8*)&Vbase[(size_t)lr * 320 + ks * 32 + g * 8];
    bf16x8 bV1 = *(const bf16x8*)&Vbase[(size_t)(16 + lr) * 320 + ks * 32 + g * 8];
    o0 = __builtin_amdgcn_mfma_f32_16x16x32_bf16(aP, bV0, o0, 0, 0, 0);
    o1 = __builtin_amdgcn_mfma_f32_16x16x32_bf16(aP, bV1, o1, 0, 0, 0);
  }

#pragma unroll
  for (int r = 0; r < 4; ++r) {
    const int q = gt * 16 + g * 4 + r;
    if (q < 300) {
      const float iv = inv[r];
      unsigned short* dst = &sa16[((size_t)b * 300 + q) * 256 + h * 32];
      dst[lr] = f2bf(o0[r] * iv);
      dst[16 + lr] = f2bf(o1[r] * iv);
    }
  }
}

// ---------------------------------------------------------------------------
// Deformable sampling -> CA16 (bf16). One block per (b,n).
// ---------------------------------------------------------------------------
__global__ __launch_bounds__(256) void deform_k(
    const float* __restrict__ memory, const float* __restrict__ refp,
    const float* __restrict__ OFF, const float* __restrict__ AW,
    unsigned short* __restrict__ ca16)
{
  __shared__ float locx[8][16], locy[8][16], wgt[8][16];
  const int bn = blockIdx.x, b = bn / 300, t = threadIdx.x;

  if (t < 128) {
    int h = t >> 4, p = t & 15;
    float cx = refp[(size_t)bn * 4 + 0], cy = refp[(size_t)bn * 4 + 1];
    float rw = refp[(size_t)bn * 4 + 2], rh = refp[(size_t)bn * 4 + 3];
    float ox = OFF[(size_t)bn * 256 + h * 32 + p * 2 + 0];
    float oy = OFF[(size_t)bn * 256 + h * 32 + p * 2 + 1];
    locx[h][p] = cx + ox * 0.125f * rw;
    locy[h][p] = cy + oy * 0.125f * rh;
    float av = AW[(size_t)bn * 128 + t];
    float mx = av;
#pragma unroll
    for (int o = 8; o; o >>= 1) mx = fmaxf(mx, __shfl_xor(mx, o));
    float e = __expf(av - mx);
    float ssum = e;
#pragma unroll
    for (int o = 8; o; o >>= 1) ssum += __shfl_xor(ssum, o);
    wgt[h][p] = e / ssum;
  }
  __syncthreads();

  const int h = t >> 5, hd = t & 31;
  const float* mb = memory + (size_t)b * 8500 * 256 + h * 32 + hd;
  float acc = 0.f;
#pragma unroll
  for (int p = 0; p < 16; ++p) {
    const int HWs[4] = {80, 40, 20, 10};
    const int Sts[4] = {0, 6400, 8000, 8400};
    const int li = p >> 2;
    const int Hh = HWs[li], Ww = HWs[li], st = Sts[li];
    float x = locx[h][p] * (float)Ww - 0.5f;
    float y = locy[h][p] * (float)Hh - 0.5f;
    float x0f = floorf(x), y0f = floorf(y);
    float dx = x - x0f, dy = y - y0f;
    int x0 = (int)x0f, y0 = (int)y0f;
    float awp = wgt[h][p];
#pragma unroll
    for (int cc = 0; cc < 4; ++cc) {
      int xi = x0 + (cc & 1), yi = y0 + (cc >> 1);
      float wc = ((cc & 1) ? dx : 1.f - dx) * ((cc >> 1) ? dy : 1.f - dy);
      bool valid = (xi >= 0) && (xi < Ww) && (yi >= 0) && (yi < Hh);
      int xc = xi < 0 ? 0 : (xi >= Ww ? Ww - 1 : xi);
      int yc = yi < 0 ? 0 : (yi >= Hh ? Hh - 1 : yi);
      float gv = mb[(size_t)(st + yc * Ww + xc) * 256];
      acc += gv * (valid ? wc * awp : 0.f);
    }
  }
  ca16[(size_t)bn * 256 + t] = f2bf(acc);
}

// ---------------------------------------------------------------------------
extern "C" void kernel_launch(void* const* d_in, const int* in_sizes, int n_in,
                              void* d_out, int out_size, void* d_ws, size_t ws_size,
                              hipStream_t stream)
{
  (void)in_sizes; (void)n_in; (void)out_size; (void)ws_size;
  const float* target  = (const float*)d_in[0];
  const float* refp    = (const float*)d_in[1];
  const float* memory  = (const float*)d_in[2];
  const float* qkv_w   = (const float*)d_in[3];
  const float* qkv_b   = (const float*)d_in[4];
  const float* out_w   = (const float*)d_in[5];
  const float* out_b   = (const float*)d_in[6];
  const float* norm1_w = (const float*)d_in[7];
  const float* off_w   = (const float*)d_in[8];
  const float* off_b   = (const float*)d_in[9];
  const float* aw_w    = (const float*)d_in[10];
  const float* aw_b    = (const float*)d_in[11];
  const float* cout_w  = (const float*)d_in[12];
  const float* cout_b  = (const float*)d_in[13];
  const float* norm2_w = (const float*)d_in[14];
  const float* w13     = (const float*)d_in[15];
  const float* w13_b   = (const float*)d_in[16];
  const float* w2      = (const float*)d_in[17];
  const float* w2_b    = (const float*)d_in[18];
  const float* norm3_w = (const float*)d_in[19];
  float* out = (float*)d_out;

  float* ws  = (float*)d_ws;
  float* X   = ws;                     // 4800*256
  float* OF  = X   + 4800 * 256;       // 4800*256
  float* AWb = OF  + 4800 * 256;       // 4800*128
  float* X2  = AWb + 4800 * 128;       // 4800*256
  float* Hb  = X2  + 4800 * 256;       // 4800*1024

  unsigned short* u   = (unsigned short*)(Hb + 4800 * 1024);
  unsigned short* Qb  = u;                         // 128*304*32 = 1245184
  unsigned short* Kb  = Qb  + 1245184;             // 1245184
  unsigned short* VTb = Kb  + 1245184;             // 128*32*320 = 1310720
  unsigned short* SA16 = VTb + 1310720;            // 4800*256 = 1228800
  unsigned short* CA16 = SA16 + 1228800;           // 1228800
  unsigned short* X16  = CA16 + 1228800;           // 1228800
  unsigned short* X216 = X16  + 1228800;           // 1228800
  unsigned short* T16  = X216 + 1228800;           // target16: 1228800
  unsigned short* qkv16  = T16  + 1228800;         // 196608
  unsigned short* out16  = qkv16  + 196608;        // 65536
  unsigned short* off16  = out16  + 65536;         // 65536
  unsigned short* aw16   = off16  + 65536;         // 32768
  unsigned short* cout16 = aw16   + 32768;         // 65536
  unsigned short* w13_16 = cout16 + 65536;         // 262144
  unsigned short* w2_16  = w13_16 + 262144;        // 131072

  dim3 blk(256);

  // 0. convert target + all weights to bf16 (one pass)
  conv_w<<<dim3(1200, 8), blk, 0, stream>>>(
      target, qkv_w, out_w, off_w, aw_w, cout_w, w13, w2,
      T16, qkv16, out16, off16, aw16, cout16, w13_16, w2_16);
  // 1. qkv GEMM (bf16 in) with fused repack (-> Qb, Kb, VTb)
  gemm_qkv16<<<dim3(6, 75), blk, 0, stream>>>(T16, qkv16, qkv_b, Qb, Kb, VTb);
  // 2. staging-free attention core -> SA16
  attn_core<<<dim3(19, 128), dim3(64), 0, stream>>>(Qb, Kb, VTb, SA16);
  // 3. X = rmsnorm(target + SA@out_w^T + out_b, norm1_w); X16 mirror
  gemm_rms32_16<false><<<150, blk, 0, stream>>>(SA16, out16, out_b, target, norm1_w, X, X16, 256, 0);
  // 4. offsets + attention-weight GEMMs (merged)
  gemm_offaw16<<<dim3(3, 75), blk, 0, stream>>>(X16, off16, off_b, OF, aw16, aw_b, AWb);
  // 5. deformable sampling -> CA16
  deform_k<<<4800, blk, 0, stream>>>(memory, refp, OF, AWb, CA16);
  // 6. X2 = rmsnorm(X + CA@cout_w^T + cout_b, norm2_w); X216 mirror
  gemm_rms32_16<false><<<150, blk, 0, stream>>>(CA16, cout16, cout_b, X, norm2_w, X2, X216, 256, 0);
  // 7. h = x2 @ w13^T + w13_b
  gemm_mfma16<<<dim3(8, 75), blk, 0, stream>>>(X216, w13_16, w13_b, Hb, 1024, 256);
  // 8. out = rmsnorm(clip(X2 + swiglu(h)@w2^T + w2_b), norm3_w)
  gemm_rms32_16<true><<<150, blk, 0, stream>>>(Hb, w2_16, w2_b, X2, norm3_w, out, nullptr, 512, 1);
}

// Round 10
// 128.639 us; speedup vs baseline: 1.3760x; 1.3760x over previous
//
#include <hip/hip_runtime.h>
#include <cstdint>
#include <cstddef>

// Problem constants
// B=16, N=300, D=256, HEADS=8, HD=32, L=8500, TP=16, HID=512
// SPATIAL = (80,80),(40,40),(20,20),(10,10); starts 0,6400,8000,8400

typedef __attribute__((ext_vector_type(8))) short bf16x8;
typedef __attribute__((ext_vector_type(4))) float f32x4;

__device__ __forceinline__ unsigned short f2bf(float f) {
  unsigned int u = __float_as_uint(f);
  u = (u + 0x7fffu + ((u >> 16) & 1u)) >> 16;   // round-to-nearest-even
  return (unsigned short)u;
}
__device__ __forceinline__ unsigned int pack2bf(float lo, float hi) {
  return ((unsigned int)f2bf(hi) << 16) | (unsigned int)f2bf(lo);
}

// ---------------------------------------------------------------------------
// Device GEMM core: C tile [row0,row0+64) x [col0,col0+128) =
// A(M,K)@W(N,K)^T + bias. bf16 MFMA, f32 in/out. 256 threads = 4 waves,
// wave owns a 32-col slab. Register-prefetch double-step pipeline.
// NOTE (r9 lesson): the f32->bf16 pack in staging is essentially free --
// it co-schedules with other resident blocks' MFMA (m114). Do not "optimize"
// it away; the bf16-at-rest rewrite regressed 131->177us.
// ---------------------------------------------------------------------------
__device__ __forceinline__ void gemm_dev(
    const float* __restrict__ A, const float* __restrict__ W,
    const float* __restrict__ bias, float* __restrict__ C,
    int N, int K, int row0, int col0,
    unsigned short* As, unsigned short* Ws)
{
  const int t = threadIdx.x, wave = t >> 6, lane = t & 63;
  const int lr = lane & 15, g = lane >> 4;
  const int sr = t >> 4, sc = (t & 15) * 4;

  float4 ra[4], rw[8];
  const float* Ab = A + (size_t)(row0 + sr) * K + sc;
  const float* Wb = W + (size_t)(col0 + sr) * K + sc;

#pragma unroll
  for (int i = 0; i < 4; ++i) ra[i] = *(const float4*)(Ab + (size_t)16 * i * K);
#pragma unroll
  for (int j = 0; j < 8; ++j) rw[j] = *(const float4*)(Wb + (size_t)16 * j * K);

  f32x4 acc[4][2] = {};

  for (int k0 = 0; k0 < K; k0 += 64) {
    __syncthreads();
#pragma unroll
    for (int i = 0; i < 4; ++i) {
      uint2 p;
      p.x = pack2bf(ra[i].x, ra[i].y);
      p.y = pack2bf(ra[i].z, ra[i].w);
      *(uint2*)&As[(sr + 16 * i) * 72 + sc] = p;
    }
#pragma unroll
    for (int j = 0; j < 8; ++j) {
      uint2 p;
      p.x = pack2bf(rw[j].x, rw[j].y);
      p.y = pack2bf(rw[j].z, rw[j].w);
      *(uint2*)&Ws[(sr + 16 * j) * 72 + sc] = p;
    }
    __syncthreads();

    if (k0 + 64 < K) {
#pragma unroll
      for (int i = 0; i < 4; ++i)
        ra[i] = *(const float4*)(Ab + (size_t)16 * i * K + k0 + 64);
#pragma unroll
      for (int j = 0; j < 8; ++j)
        rw[j] = *(const float4*)(Wb + (size_t)16 * j * K + k0 + 64);
    }

#pragma unroll
    for (int ks = 0; ks < 2; ++ks) {
      bf16x8 aA[4], bB[2];
#pragma unroll
      for (int i = 0; i < 4; ++i)
        aA[i] = *(const bf16x8*)&As[(i * 16 + lr) * 72 + ks * 32 + g * 8];
#pragma unroll
      for (int j = 0; j < 2; ++j)
        bB[j] = *(const bf16x8*)&Ws[(wave * 32 + j * 16 + lr) * 72 + ks * 32 + g * 8];
#pragma unroll
      for (int i = 0; i < 4; ++i)
#pragma unroll
        for (int j = 0; j < 2; ++j)
          acc[i][j] = __builtin_amdgcn_mfma_f32_16x16x32_bf16(aA[i], bB[j], acc[i][j], 0, 0, 0);
    }
  }

  const float b0 = bias[col0 + wave * 32 + lr];
  const float b1 = bias[col0 + wave * 32 + 16 + lr];
#pragma unroll
  for (int i = 0; i < 4; ++i) {
#pragma unroll
    for (int r = 0; r < 4; ++r) {
      const int row = row0 + i * 16 + g * 4 + r;
      float* dst = &C[(size_t)row * N + col0 + wave * 32 + lr];
      dst[0]  = acc[i][0][r] + b0;
      dst[16] = acc[i][1][r] + b1;
    }
  }
}

__global__ __launch_bounds__(256) void gemm_mfma(
    const float* __restrict__ A, const float* __restrict__ W,
    const float* __restrict__ bias, float* __restrict__ C, int N, int K)
{
  __shared__ __align__(16) unsigned short As[64 * 72];
  __shared__ __align__(16) unsigned short Ws[128 * 72];
  gemm_dev(A, W, bias, C, N, K, blockIdx.y * 64, blockIdx.x * 128, As, Ws);
}

// OF (N=256, blocks 0,1) and AW (N=128, block 2) share input X.
__global__ __launch_bounds__(256) void gemm_offaw(
    const float* __restrict__ X,
    const float* __restrict__ off_w, const float* __restrict__ off_b, float* __restrict__ OF,
    const float* __restrict__ aw_w, const float* __restrict__ aw_b, float* __restrict__ AW,
    int K)
{
  __shared__ __align__(16) unsigned short As[64 * 72];
  __shared__ __align__(16) unsigned short Ws[128 * 72];
  if (blockIdx.x < 2)
    gemm_dev(X, off_w, off_b, OF, 256, K, blockIdx.y * 64, blockIdx.x * 128, As, Ws);
  else
    gemm_dev(X, aw_w, aw_b, AW, 128, K, blockIdx.y * 64, 0, As, Ws);
}

// ---------------------------------------------------------------------------
// Fused GEMM + residual + [clip] + RMSNorm. Tile 32(M) x 256(N=full row),
// grid 150 blocks, 4 waves; wave owns a 64-col slab (acc[2][4]).
// Register-prefetch pipeline identical to gemm_dev.
// SWIGLU variant: A = silu(h1)*h2 from Hb stride 1024 (h2 at +512), K=512.
// C = rmsnorm(res + A@W^T + bias [clip], nw).
// ---------------------------------------------------------------------------
template <bool SWIGLU>
__global__ __launch_bounds__(256) void gemm_rms32(
    const float* __restrict__ A, const float* __restrict__ W,
    const float* __restrict__ bias, const float* __restrict__ res,
    const float* __restrict__ nw, float* __restrict__ C,
    int K, int clip)
{
  __shared__ __align__(16) unsigned short As[32 * 72];
  __shared__ __align__(16) unsigned short Ws[256 * 72];
  __shared__ float rsum[32][4];

  const int t = threadIdx.x, wave = t >> 6, lane = t & 63;
  const int lr = lane & 15, g = lane >> 4;
  const int row0 = blockIdx.x * 32;
  const int sr = t >> 4, sc = (t & 15) * 4;
  const int Astride = SWIGLU ? 1024 : K;

  float4 ra1[2], ra2[2], rw[16];
  const float* Ab = A + (size_t)(row0 + sr) * Astride + sc;
  const float* Wb = W + (size_t)sr * K + sc;

#pragma unroll
  for (int i = 0; i < 2; ++i) {
    ra1[i] = *(const float4*)(Ab + (size_t)16 * i * Astride);
    if (SWIGLU) ra2[i] = *(const float4*)(Ab + (size_t)16 * i * Astride + 512);
  }
#pragma unroll
  for (int j = 0; j < 16; ++j) rw[j] = *(const float4*)(Wb + (size_t)16 * j * K);

  f32x4 acc[2][4] = {};

  for (int k0 = 0; k0 < K; k0 += 64) {
    __syncthreads();
#pragma unroll
    for (int i = 0; i < 2; ++i) {
      float4 v;
      if (SWIGLU) {
        v.x = ra1[i].x / (1.f + __expf(-ra1[i].x)) * ra2[i].x;
        v.y = ra1[i].y / (1.f + __expf(-ra1[i].y)) * ra2[i].y;
        v.z = ra1[i].z / (1.f + __expf(-ra1[i].z)) * ra2[i].z;
        v.w = ra1[i].w / (1.f + __expf(-ra1[i].w)) * ra2[i].w;
      } else {
        v = ra1[i];
      }
      uint2 p;
      p.x = pack2bf(v.x, v.y);
      p.y = pack2bf(v.z, v.w);
      *(uint2*)&As[(sr + 16 * i) * 72 + sc] = p;
    }
#pragma unroll
    for (int j = 0; j < 16; ++j) {
      uint2 p;
      p.x = pack2bf(rw[j].x, rw[j].y);
      p.y = pack2bf(rw[j].z, rw[j].w);
      *(uint2*)&Ws[(sr + 16 * j) * 72 + sc] = p;
    }
    __syncthreads();

    if (k0 + 64 < K) {
#pragma unroll
      for (int i = 0; i < 2; ++i) {
        ra1[i] = *(const float4*)(Ab + (size_t)16 * i * Astride + k0 + 64);
        if (SWIGLU) ra2[i] = *(const float4*)(Ab + (size_t)16 * i * Astride + 512 + k0 + 64);
      }
#pragma unroll
      for (int j = 0; j < 16; ++j)
        rw[j] = *(const float4*)(Wb + (size_t)16 * j * K + k0 + 64);
    }

#pragma unroll
    for (int ks = 0; ks < 2; ++ks) {
      bf16x8 aA[2], bB[4];
#pragma unroll
      for (int i = 0; i < 2; ++i)
        aA[i] = *(const bf16x8*)&As[(i * 16 + lr) * 72 + ks * 32 + g * 8];
#pragma unroll
      for (int j = 0; j < 4; ++j)
        bB[j] = *(const bf16x8*)&Ws[(wave * 64 + j * 16 + lr) * 72 + ks * 32 + g * 8];
#pragma unroll
      for (int i = 0; i < 2; ++i)
#pragma unroll
        for (int j = 0; j < 4; ++j)
          acc[i][j] = __builtin_amdgcn_mfma_f32_16x16x32_bf16(aA[i], bB[j], acc[i][j], 0, 0, 0);
    }
  }

  // ---- epilogue: v = acc + bias + res [clip]; row sumsq; rmsnorm; store
  float bj[4], wj[4];
#pragma unroll
  for (int j = 0; j < 4; ++j) {
    bj[j] = bias[wave * 64 + j * 16 + lr];
    wj[j] = nw[wave * 64 + j * 16 + lr];
  }

  float part[2][4] = {};
#pragma unroll
  for (int i = 0; i < 2; ++i) {
#pragma unroll
    for (int r = 0; r < 4; ++r) {
      const int row = row0 + i * 16 + g * 4 + r;
#pragma unroll
      for (int j = 0; j < 4; ++j) {
        const int col = wave * 64 + j * 16 + lr;
        float v = acc[i][j][r] + bj[j] + res[(size_t)row * 256 + col];
        if (clip) v = fminf(fmaxf(v, -65504.f), 65504.f);
        acc[i][j][r] = v;
        part[i][r] += v * v;
      }
    }
  }
#pragma unroll
  for (int i = 0; i < 2; ++i)
#pragma unroll
    for (int r = 0; r < 4; ++r) {
      float s = part[i][r];
      s += __shfl_xor(s, 1);
      s += __shfl_xor(s, 2);
      s += __shfl_xor(s, 4);
      s += __shfl_xor(s, 8);
      part[i][r] = s;
    }
  if (lr == 0) {
#pragma unroll
    for (int i = 0; i < 2; ++i)
#pragma unroll
      for (int r = 0; r < 4; ++r)
        rsum[i * 16 + g * 4 + r][wave] = part[i][r];
  }
  __syncthreads();

#pragma unroll
  for (int i = 0; i < 2; ++i) {
#pragma unroll
    for (int r = 0; r < 4; ++r) {
      const int row = row0 + i * 16 + g * 4 + r;
      const f32x4 q = *(const f32x4*)&rsum[i * 16 + g * 4 + r][0];
      const float tot = q[0] + q[1] + q[2] + q[3];
      const float scale = rsqrtf(tot * (1.0f / 256.0f) + 1e-6f);
#pragma unroll
      for (int j = 0; j < 4; ++j) {
        const int col = wave * 64 + j * 16 + lr;
        C[(size_t)row * 256 + col] = acc[i][j][r] * scale * wj[j];
      }
    }
  }
}

// ---------------------------------------------------------------------------
// QKV GEMM with fused bf16 repack epilogue. A=target (4800x256),
// W=qkv_w (768x256). Slabs: bx 0,1 -> Qb (scaled); 2,3 -> Kb; 4,5 -> VTb
// (transposed via LDS bounce, reusing Ws after the K-loop).
//   Qb/Kb: [bh][304][32]; VTb: [bh][32][320] (cols 300..319 zeroed by y==74)
// ---------------------------------------------------------------------------
__global__ __launch_bounds__(256) void gemm_qkv(
    const float* __restrict__ A, const float* __restrict__ W,
    const float* __restrict__ bias,
    unsigned short* __restrict__ Qb, unsigned short* __restrict__ Kb,
    unsigned short* __restrict__ VTb)
{
  __shared__ __align__(16) unsigned short As[64 * 72];
  __shared__ __align__(16) unsigned short Ws[128 * 72];
  const int K = 256;
  const int t = threadIdx.x, wave = t >> 6, lane = t & 63;
  const int lr = lane & 15, g = lane >> 4;
  const int row0 = blockIdx.y * 64, col0 = blockIdx.x * 128;
  const int sr = t >> 4, sc = (t & 15) * 4;

  float4 ra[4], rw[8];
  const float* Ab = A + (size_t)(row0 + sr) * K + sc;
  const float* Wb = W + (size_t)(col0 + sr) * K + sc;

#pragma unroll
  for (int i = 0; i < 4; ++i) ra[i] = *(const float4*)(Ab + (size_t)16 * i * K);
#pragma unroll
  for (int j = 0; j < 8; ++j) rw[j] = *(const float4*)(Wb + (size_t)16 * j * K);

  f32x4 acc[4][2] = {};

  for (int k0 = 0; k0 < K; k0 += 64) {
    __syncthreads();
#pragma unroll
    for (int i = 0; i < 4; ++i) {
      uint2 p;
      p.x = pack2bf(ra[i].x, ra[i].y);
      p.y = pack2bf(ra[i].z, ra[i].w);
      *(uint2*)&As[(sr + 16 * i) * 72 + sc] = p;
    }
#pragma unroll
    for (int j = 0; j < 8; ++j) {
      uint2 p;
      p.x = pack2bf(rw[j].x, rw[j].y);
      p.y = pack2bf(rw[j].z, rw[j].w);
      *(uint2*)&Ws[(sr + 16 * j) * 72 + sc] = p;
    }
    __syncthreads();

    if (k0 + 64 < K) {
#pragma unroll
      for (int i = 0; i < 4; ++i)
        ra[i] = *(const float4*)(Ab + (size_t)16 * i * K + k0 + 64);
#pragma unroll
      for (int j = 0; j < 8; ++j)
        rw[j] = *(const float4*)(Wb + (size_t)16 * j * K + k0 + 64);
    }

#pragma unroll
    for (int ks = 0; ks < 2; ++ks) {
      bf16x8 aA[4], bB[2];
#pragma unroll
      for (int i = 0; i < 4; ++i)
        aA[i] = *(const bf16x8*)&As[(i * 16 + lr) * 72 + ks * 32 + g * 8];
#pragma unroll
      for (int j = 0; j < 2; ++j)
        bB[j] = *(const bf16x8*)&Ws[(wave * 32 + j * 16 + lr) * 72 + ks * 32 + g * 8];
#pragma unroll
      for (int i = 0; i < 4; ++i)
#pragma unroll
        for (int j = 0; j < 2; ++j)
          acc[i][j] = __builtin_amdgcn_mfma_f32_16x16x32_bf16(aA[i], bB[j], acc[i][j], 0, 0, 0);
    }
  }

  const int bx = blockIdx.x;
  const float scale = 0.17677669529663687f;  // 1/sqrt(32)
  const float b0 = bias[col0 + wave * 32 + lr];
  const float b1 = bias[col0 + wave * 32 + 16 + lr];

  if (bx < 4) {
    unsigned short* dstT = (bx < 2) ? Qb : Kb;
    const float mul = (bx < 2) ? scale : 1.0f;
#pragma unroll
    for (int i = 0; i < 4; ++i) {
#pragma unroll
      for (int r = 0; r < 4; ++r) {
        const int row = row0 + i * 16 + g * 4 + r;
        const int b = row / 300, n = row - b * 300;
#pragma unroll
        for (int j = 0; j < 2; ++j) {
          const int c768 = col0 + wave * 32 + j * 16 + lr;
          const int h = (c768 >> 5) & 7, c = c768 & 31;
          const float v = (acc[i][j][r] + (j ? b1 : b0)) * mul;
          dstT[((size_t)(b * 8 + h) * 304 + n) * 32 + c] = f2bf(v);
        }
      }
    }
  } else {
    __syncthreads();
#pragma unroll
    for (int i = 0; i < 4; ++i)
#pragma unroll
      for (int r = 0; r < 4; ++r)
#pragma unroll
        for (int j = 0; j < 2; ++j) {
          const int c_local = wave * 32 + j * 16 + lr;
          const int n_local = i * 16 + g * 4 + r;
          Ws[c_local * 72 + n_local] = f2bf(acc[i][j][r] + (j ? b1 : b0));
        }
    __syncthreads();
    for (int idx = t; idx < 128 * 64; idx += 256) {
      const int c_local = idx >> 6, n_local = idx & 63;
      const int row = row0 + n_local;
      const int b = row / 300, n = row - b * 300;
      const int c768 = col0 + c_local;
      const int h = (c768 >> 5) & 7, c = c768 & 31;
      VTb[((size_t)(b * 8 + h) * 32 + c) * 320 + n] = Ws[c_local * 72 + n_local];
    }
    if (blockIdx.y == 74) {
      for (int idx = t; idx < 64 * 32 * 20; idx += 256) {
        const int n = 300 + idx % 20;
        const int rem = idx / 20;
        const int c = rem & 31, bh4 = rem >> 5;
        const int b = bh4 >> 2, h = (bx - 4) * 4 + (bh4 & 3);
        VTb[((size_t)(b * 8 + h) * 32 + c) * 320 + n] = 0;
      }
    }
  }
}

// ---------------------------------------------------------------------------
// Staging-free MFMA self-attention core. grid (19 q-tiles, B*H), block = 1
// wave. Q/K/V fragments are direct 16B global loads (L2-hot bf16 tensors).
// ---------------------------------------------------------------------------
__global__ __launch_bounds__(64) void attn_core(
    const unsigned short* __restrict__ Qb, const unsigned short* __restrict__ Kb,
    const unsigned short* __restrict__ VTb, float* __restrict__ sa)
{
  __shared__ __align__(16) unsigned short P[16 * 40];
  const int gt = blockIdx.x;               // q-tile 0..18
  const int bh = blockIdx.y, b = bh >> 3, h = bh & 7;
  const int lane = threadIdx.x, lr = lane & 15, g = lane >> 4;

  const unsigned short* Kbase = Kb + (size_t)bh * 304 * 32;
  const unsigned short* Vbase = VTb + (size_t)bh * 32 * 320;

  bf16x8 aQ = *(const bf16x8*)&Qb[((size_t)bh * 304 + gt * 16 + lr) * 32 + g * 8];

  f32x4 s[19];
  const f32x4 zero = {0.f, 0.f, 0.f, 0.f};
#pragma unroll
  for (int kt = 0; kt < 19; ++kt) {
    bf16x8 bK = *(const bf16x8*)&Kbase[(kt * 16 + lr) * 32 + g * 8];
    s[kt] = __builtin_amdgcn_mfma_f32_16x16x32_bf16(aQ, bK, zero, 0, 0, 0);
  }
  if (lr >= 12) {  // mask cols 300..303
    s[18][0] = -1e30f; s[18][1] = -1e30f; s[18][2] = -1e30f; s[18][3] = -1e30f;
  }

  float inv[4];
#pragma unroll
  for (int r = 0; r < 4; ++r) {
    float m = -1e30f;
#pragma unroll
    for (int kt = 0; kt < 19; ++kt) m = fmaxf(m, s[kt][r]);
#pragma unroll
    for (int o = 8; o >= 1; o >>= 1) m = fmaxf(m, __shfl_xor(m, o));
    float sum = 0.f;
#pragma unroll
    for (int kt = 0; kt < 19; ++kt) {
      float e = __expf(s[kt][r] - m);
      s[kt][r] = e;
      sum += e;
    }
#pragma unroll
    for (int o = 8; o >= 1; o >>= 1) sum += __shfl_xor(sum, o);
    inv[r] = 1.f / sum;
  }

  f32x4 o0 = {0.f, 0.f, 0.f, 0.f}, o1 = {0.f, 0.f, 0.f, 0.f};
#pragma unroll
  for (int ks = 0; ks < 10; ++ks) {
#pragma unroll
    for (int tp = 0; tp < 2; ++tp) {
      const int kt = ks * 2 + tp;
#pragma unroll
      for (int r = 0; r < 4; ++r) {
        unsigned short pv = (kt < 19) ? f2bf(s[kt][r]) : (unsigned short)0;
        P[(g * 4 + r) * 40 + tp * 16 + lr] = pv;
      }
    }
    asm volatile("s_waitcnt lgkmcnt(0)" ::: "memory");
    __builtin_amdgcn_sched_barrier(0);
    bf16x8 aP = *(const bf16x8*)&P[lr * 40 + g * 8];
    bf16x8 bV0 = *(const bf16x8*)&Vbase[(size_t)lr * 320 + ks * 32 + g * 8];
    bf16x8 bV1 = *(const bf16x8*)&Vbase[(size_t)(16 + lr) * 320 + ks * 32 + g * 8];
    o0 = __builtin_amdgcn_mfma_f32_16x16x32_bf16(aP, bV0, o0, 0, 0, 0);
    o1 = __builtin_amdgcn_mfma_f32_16x16x32_bf16(aP, bV1, o1, 0, 0, 0);
  }

#pragma unroll
  for (int r = 0; r < 4; ++r) {
    const int q = gt * 16 + g * 4 + r;
    if (q < 300) {
      const float iv = inv[r];
      float* dst = &sa[((size_t)b * 300 + q) * 256 + h * 32];
      dst[lr] = o0[r] * iv;
      dst[16 + lr] = o1[r] * iv;
    }
  }
}

// ---------------------------------------------------------------------------
// Deformable sampling. One block per (b,n), XCD-swizzled: blockIdx i ->
// bn = (i&7)*600 + (i>>3), so (assuming round-robin blockIdx%8 -> XCD)
// XCD x runs exactly images {2x, 2x+1} -> per-XCD L2 gather working set
// drops from all 16 images (139MB) to 2 (17MB, touched subset smaller).
// ---------------------------------------------------------------------------
__global__ __launch_bounds__(256) void deform_k(
    const float* __restrict__ memory, const float* __restrict__ refp,
    const float* __restrict__ OFF, const float* __restrict__ AW,
    float* __restrict__ ca)
{
  __shared__ float locx[8][16], locy[8][16], wgt[8][16];
  const int i = blockIdx.x;
  const int bn = (i & 7) * 600 + (i >> 3);   // bijective: 4800 = 8*600
  const int b = bn / 300, t = threadIdx.x;

  if (t < 128) {
    int h = t >> 4, p = t & 15;
    float cx = refp[(size_t)bn * 4 + 0], cy = refp[(size_t)bn * 4 + 1];
    float rw = refp[(size_t)bn * 4 + 2], rh = refp[(size_t)bn * 4 + 3];
    float ox = OFF[(size_t)bn * 256 + h * 32 + p * 2 + 0];
    float oy = OFF[(size_t)bn * 256 + h * 32 + p * 2 + 1];
    locx[h][p] = cx + ox * 0.125f * rw;
    locy[h][p] = cy + oy * 0.125f * rh;
    float av = AW[(size_t)bn * 128 + t];
    float mx = av;
#pragma unroll
    for (int o = 8; o; o >>= 1) mx = fmaxf(mx, __shfl_xor(mx, o));
    float e = __expf(av - mx);
    float ssum = e;
#pragma unroll
    for (int o = 8; o; o >>= 1) ssum += __shfl_xor(ssum, o);
    wgt[h][p] = e / ssum;
  }
  __syncthreads();

  const int h = t >> 5, hd = t & 31;
  const float* mb = memory + (size_t)b * 8500 * 256 + h * 32 + hd;
  float acc = 0.f;
#pragma unroll
  for (int p = 0; p < 16; ++p) {
    const int HWs[4] = {80, 40, 20, 10};
    const int Sts[4] = {0, 6400, 8000, 8400};
    const int li = p >> 2;
    const int Hh = HWs[li], Ww = HWs[li], st = Sts[li];
    float x = locx[h][p] * (float)Ww - 0.5f;
    float y = locy[h][p] * (float)Hh - 0.5f;
    float x0f = floorf(x), y0f = floorf(y);
    float dx = x - x0f, dy = y - y0f;
    int x0 = (int)x0f, y0 = (int)y0f;
    float awp = wgt[h][p];
#pragma unroll
    for (int cc = 0; cc < 4; ++cc) {
      int xi = x0 + (cc & 1), yi = y0 + (cc >> 1);
      float wc = ((cc & 1) ? dx : 1.f - dx) * ((cc >> 1) ? dy : 1.f - dy);
      bool valid = (xi >= 0) && (xi < Ww) && (yi >= 0) && (yi < Hh);
      int xc = xi < 0 ? 0 : (xi >= Ww ? Ww - 1 : xi);
      int yc = yi < 0 ? 0 : (yi >= Hh ? Hh - 1 : yi);
      float gv = mb[(size_t)(st + yc * Ww + xc) * 256];
      acc += gv * (valid ? wc * awp : 0.f);
    }
  }
  ca[(size_t)bn * 256 + t] = acc;
}

// ---------------------------------------------------------------------------
extern "C" void kernel_launch(void* const* d_in, const int* in_sizes, int n_in,
                              void* d_out, int out_size, void* d_ws, size_t ws_size,
                              hipStream_t stream)
{
  (void)in_sizes; (void)n_in; (void)out_size; (void)ws_size;
  const float* target  = (const float*)d_in[0];
  const float* refp    = (const float*)d_in[1];
  const float* memory  = (const float*)d_in[2];
  const float* qkv_w   = (const float*)d_in[3];
  const float* qkv_b   = (const float*)d_in[4];
  const float* out_w   = (const float*)d_in[5];
  const float* out_b   = (const float*)d_in[6];
  const float* norm1_w = (const float*)d_in[7];
  const float* off_w   = (const float*)d_in[8];
  const float* off_b   = (const float*)d_in[9];
  const float* aw_w    = (const float*)d_in[10];
  const float* aw_b    = (const float*)d_in[11];
  const float* cout_w  = (const float*)d_in[12];
  const float* cout_b  = (const float*)d_in[13];
  const float* norm2_w = (const float*)d_in[14];
  const float* w13     = (const float*)d_in[15];
  const float* w13_b   = (const float*)d_in[16];
  const float* w2      = (const float*)d_in[17];
  const float* w2_b    = (const float*)d_in[18];
  const float* norm3_w = (const float*)d_in[19];
  float* out = (float*)d_out;

  float* ws  = (float*)d_ws;
  float* SA  = ws;                     // 4800*256
  float* X   = SA  + 4800 * 256;       // 4800*256
  float* OF  = X   + 4800 * 256;       // 4800*256
  float* AWb = OF  + 4800 * 256;       // 4800*128
  float* CA  = AWb + 4800 * 128;       // 4800*256
  float* X2  = CA  + 4800 * 256;       // 4800*256
  float* Hb  = X2  + 4800 * 256;       // 4800*1024
  unsigned short* Qb  = (unsigned short*)(Hb + 4800 * 1024);  // 128*304*32
  unsigned short* Kb  = Qb + 128 * 304 * 32;                  // 128*304*32
  unsigned short* VTb = Kb + 128 * 304 * 32;                  // 128*32*320

  dim3 blk(256);

  // 1. qkv GEMM with fused bf16 repack (-> Qb, Kb, VTb)
  gemm_qkv<<<dim3(6, 75), blk, 0, stream>>>(target, qkv_w, qkv_b, Qb, Kb, VTb);
  // 2. staging-free attention core
  attn_core<<<dim3(19, 128), dim3(64), 0, stream>>>(Qb, Kb, VTb, SA);
  // 3. X = rmsnorm(target + SA@out_w^T + out_b, norm1_w)   [fused]
  gemm_rms32<false><<<150, blk, 0, stream>>>(SA, out_w, out_b, target, norm1_w, X, 256, 0);
  // 4. offsets + attention-weight GEMMs (merged launch)
  gemm_offaw<<<dim3(3, 75), blk, 0, stream>>>(X, off_w, off_b, OF, aw_w, aw_b, AWb, 256);
  // 5. deformable sampling (XCD-swizzled)
  deform_k<<<4800, blk, 0, stream>>>(memory, refp, OF, AWb, CA);
  // 6. X2 = rmsnorm(X + CA@cout_w^T + cout_b, norm2_w)     [fused]
  gemm_rms32<false><<<150, blk, 0, stream>>>(CA, cout_w, cout_b, X, norm2_w, X2, 256, 0);
  // 7. h = x2 @ w13^T + w13_b
  gemm_mfma<<<dim3(8, 75), blk, 0, stream>>>(X2, w13, w13_b, Hb, 1024, 256);
  // 8. out = rmsnorm(clip(X2 + swiglu(h)@w2^T + w2_b), norm3_w)  [fused]
  gemm_rms32<true><<<150, blk, 0, stream>>>(Hb, w2, w2_b, X2, norm3_w, out, 512, 1);
}